// Round 11
// baseline (238.290 us; speedup 1.0000x reference)
//
#include <hip/hip_runtime.h>
#include <math.h>

#define N_NODES 50000
#define N_EDGES 1600000
#define IN_DIM 256
#define HID_DIM 128
#define OUT_DIM 40
#define N2 48          // OUT_DIM padded to MFMA multiple
#define H2S 40         // h2b row stride (elems): 4.0 MB -> per-XCD L2 resident
#define ZROW N_NODES   // dedicated all-zero row index for CSR padding
#define NROWS 50048    // row allocation (covers pad + tile overrun)
#define NPERM 50176    // perm slots (196 buckets x 256)

#define NB 196         // dst buckets of 256 nodes
#define BCAP 10240     // part[] slots per bucket
#define SEGSTRIDE 12288
#define PCHUNK 8192
#define NPB ((N_EDGES + PCHUNK - 1) / PCHUNK)  // 196

typedef __attribute__((ext_vector_type(8))) short bf16x8;
typedef __attribute__((ext_vector_type(4))) float f32x4;
typedef __attribute__((ext_vector_type(2))) float f32x2;

// ---------------- bf16 helpers ----------------
__device__ __forceinline__ unsigned int f2bf(float f) {
    unsigned int u = __float_as_uint(f);
    unsigned int r = u + 0x7FFFu + ((u >> 16) & 1u);
    return r >> 16;
}
__device__ __forceinline__ float bfl(unsigned int u) { return __uint_as_float(u << 16); }
__device__ __forceinline__ float bfh(unsigned int u) { return __uint_as_float(u & 0xffff0000u); }
__device__ __forceinline__ float bf2f(unsigned short s) {
    return __uint_as_float(((unsigned int)s) << 16);
}

// ---------------- prep: gcursor bases, zero rows, w1t, w2t ----------------
__global__ __launch_bounds__(256) void k_prep(const float* __restrict__ W1,
                                              const float* __restrict__ W2,
                                              int* __restrict__ gcursor,
                                              unsigned short* __restrict__ w1t,
                                              unsigned short* __restrict__ w2t,
                                              unsigned short* __restrict__ h1b,
                                              unsigned short* __restrict__ h2b) {
    const int b = blockIdx.x, t = threadIdx.x;
    if (b == 0) {
        if (t < NB) gcursor[t] = t * BCAP;
        if (t < HID_DIM) h1b[(size_t)ZROW * HID_DIM + t] = 0;
        if (t < H2S) h2b[(size_t)ZROW * H2S + t] = 0;
        for (int i = t; i < N2 * HID_DIM; i += 256) {
            int c = i >> 7, k = i & 127;
            w2t[i] = (c < OUT_DIM) ? (unsigned short)f2bf(W2[k * OUT_DIM + c]) : (unsigned short)0;
        }
    } else {
        int c = b - 1;
        w1t[c * IN_DIM + t] = (unsigned short)f2bf(W1[t * HID_DIM + c]);
    }
}

// ---------------- partition edges into 196 dst-buckets (4B packed) ----------------
__global__ __launch_bounds__(256) void k_part(const int* __restrict__ src,
                                              const int* __restrict__ dst,
                                              int* __restrict__ gcursor,
                                              unsigned int* __restrict__ part) {
    __shared__ int hist[NB];
    __shared__ int lcur[NB];
    const int tid = threadIdx.x;
    const int base = blockIdx.x * PCHUNK;
    const int n = min(PCHUNK, N_EDGES - base);

    for (int i = tid; i < NB; i += 256) hist[i] = 0;
    __syncthreads();
    for (int i = tid; i < n; i += 256)
        atomicAdd(&hist[dst[base + i] >> 8], 1);
    __syncthreads();
    for (int i = tid; i < NB; i += 256)
        lcur[i] = atomicAdd(&gcursor[i], hist[i]);
    __syncthreads();
    for (int i = tid; i < n; i += 256) {
        int d = dst[base + i];
        int g = d >> 8;
        int pos = atomicAdd(&lcur[g], 1);
        part[pos] = ((unsigned int)(d & 255) << 16) | (unsigned int)src[base + i];
    }
}

// ---------------- per-bucket counting sort + degree-sorted perm ----------------
__global__ __launch_bounds__(256) void k_bucket(const unsigned int* __restrict__ part,
                                                const int* __restrict__ gcursor,
                                                int* __restrict__ row_beg,
                                                int* __restrict__ row_end,
                                                float* __restrict__ dinv,
                                                int* __restrict__ csr,
                                                int* __restrict__ perm) {
    __shared__ int hist[256];
    __shared__ int sh[256];
    __shared__ int cur[256];
    __shared__ int dcur[128];
    const int g = blockIdx.x;
    const int tid = threadIdx.x;
    const int ebase = g * BCAP;
    const int ecnt = gcursor[g] - ebase;
    const int cbase = g * SEGSTRIDE;

    hist[tid] = 0;
    __syncthreads();
    for (int i = tid; i < ecnt; i += 256)
        atomicAdd(&hist[(part[ebase + i] >> 16) & 255], 1);
    __syncthreads();

    const int own = hist[tid];
    int pcnt = (own + 7) & ~7;
    sh[tid] = pcnt;
    __syncthreads();
    for (int off = 1; off < 256; off <<= 1) {
        int t = (tid >= off) ? sh[tid - off] : 0;
        __syncthreads();
        sh[tid] += t;
        __syncthreads();
    }
    int pexcl = sh[tid] - pcnt;

    const int node = (g << 8) + tid;
    if (node < N_NODES) {
        row_beg[node] = cbase + pexcl;
        row_end[node] = cbase + pexcl + pcnt;
        dinv[node] = rsqrtf((float)own + 1.0f);
    }
    cur[tid] = cbase + pexcl;
    for (int p = own; p < pcnt; ++p) csr[cbase + pexcl + p] = ZROW;
    __syncthreads();

    for (int i = tid; i < ecnt; i += 256) {
        unsigned int p = part[ebase + i];
        int pos = atomicAdd(&cur[(p >> 16) & 255], 1);
        csr[pos] = (int)(p & 0xFFFFu);
    }
    __syncthreads();

    // ---- degree-class counting sort -> perm (descending degree; invalid last) ----
    const int key = (node < N_NODES) ? (min(own, 126) + 1) : 0;  // 1..127 valid, 0 invalid
    if (tid < 128) { sh[tid] = 0; dcur[tid] = 0; }
    __syncthreads();
    atomicAdd(&sh[key], 1);
    __syncthreads();
    // inclusive scan over 128 bins (Hillis-Steele, all-thread barriers)
    for (int off = 1; off < 128; off <<= 1) {
        int t = (tid < 128 && tid >= off) ? sh[tid - off] : 0;
        __syncthreads();
        if (tid < 128) sh[tid] += t;
        __syncthreads();
    }
    int base_desc = 256 - sh[key];               // count of keys > key
    int rank = base_desc + atomicAdd(&dcur[key], 1);
    perm[(g << 8) + rank] = node;
}

// ---------------- GEMM1 (MFMA): h1b[N][128](bf16) = dinv * (x @ W1) ----------------
__global__ __launch_bounds__(256) void k_gemm1_mfma(const float* __restrict__ x,
                                                    const unsigned short* __restrict__ w1t,
                                                    const float* __restrict__ dinv,
                                                    unsigned short* __restrict__ h1b) {
    __shared__ unsigned short Asub[128 * 32];
    __shared__ unsigned short Bsub[128 * 32];
    const int tid  = threadIdx.x;
    const int w    = tid >> 6;
    const int lane = tid & 63;
    const int row0 = blockIdx.x * 128;
    const int r  = lane & 15;
    const int kg = lane >> 4;

    f32x4 acc[2][8] = {};

    for (int k0 = 0; k0 < IN_DIM; k0 += 32) {
#pragma unroll
        for (int i = 0; i < 2; ++i) {
            int q = tid + i * 256;
            int ar = q >> 2, as = q & 3;
            int asw = as ^ (ar & 3);
            uint4 pk = make_uint4(0, 0, 0, 0);
            int grow = row0 + ar;
            if (grow < N_NODES) {
                const float4* p = (const float4*)(x + (size_t)grow * IN_DIM + k0 + as * 8);
                float4 v0 = p[0], v1 = p[1];
                pk.x = f2bf(v0.x) | (f2bf(v0.y) << 16);
                pk.y = f2bf(v0.z) | (f2bf(v0.w) << 16);
                pk.z = f2bf(v1.x) | (f2bf(v1.y) << 16);
                pk.w = f2bf(v1.z) | (f2bf(v1.w) << 16);
            }
            *(uint4*)(Asub + ar * 32 + asw * 8) = pk;
        }
#pragma unroll
        for (int i = 0; i < 2; ++i) {
            int q = tid + i * 256;
            int col = q >> 2, slot = q & 3;
            int sl2 = slot ^ (col & 3);
            *(uint4*)(Bsub + col * 32 + sl2 * 8) =
                *(const uint4*)(w1t + (size_t)col * IN_DIM + k0 + slot * 8);
        }
        __syncthreads();

        bf16x8 af0 = *(const bf16x8*)(Asub + (w * 32 + r) * 32 + ((kg ^ (r & 3)) * 8));
        bf16x8 af1 = *(const bf16x8*)(Asub + (w * 32 + 16 + r) * 32 + ((kg ^ (r & 3)) * 8));
#pragma unroll
        for (int f = 0; f < 8; ++f) {
            bf16x8 bfr = *(const bf16x8*)(Bsub + (f * 16 + r) * 32 + ((kg ^ (r & 3)) * 8));
            acc[0][f] = __builtin_amdgcn_mfma_f32_16x16x32_bf16(af0, bfr, acc[0][f], 0, 0, 0);
            acc[1][f] = __builtin_amdgcn_mfma_f32_16x16x32_bf16(af1, bfr, acc[1][f], 0, 0, 0);
        }
        __syncthreads();
    }

#pragma unroll
    for (int a = 0; a < 2; ++a) {
        float dv[4];
#pragma unroll
        for (int v = 0; v < 4; ++v) {
            int gr = row0 + w * 32 + a * 16 + kg * 4 + v;
            dv[v] = (gr < N_NODES) ? dinv[gr] : 0.f;
        }
#pragma unroll
        for (int f = 0; f < 8; ++f)
#pragma unroll
            for (int v = 0; v < 4; ++v) {
                int gr = row0 + w * 32 + a * 16 + kg * 4 + v;
                if (gr < N_NODES)
                    h1b[(size_t)gr * HID_DIM + f * 16 + r] =
                        (unsigned short)f2bf(acc[a][f][v] * dv[v]);
            }
    }
}

// ---------------- layer-1 gather: XCD-affine slices, node-owned 4-lane groups ----------------
// blockIdx&7 -> (slice,sub); block covers 64 degree-sorted nodes; group (4 lanes)
// owns one node, gathers its 64B slice-line per edge via one uint4 load.
__global__ __launch_bounds__(256) void k_layer1(const unsigned short* __restrict__ h1b,
                                                const float* __restrict__ dinv,
                                                const float* __restrict__ b1,
                                                const int* __restrict__ row_beg,
                                                const int* __restrict__ row_end,
                                                const int* __restrict__ csr,
                                                const int* __restrict__ perm,
                                                unsigned short* __restrict__ h1a) {
    const int tid  = threadIdx.x;
    const int u     = blockIdx.x & 7;
    const int slice = u >> 1;
    const int ng    = (blockIdx.x >> 3) * 2 + (u & 1);   // 0..781
    const int w    = tid >> 6;
    const int lane = tid & 63;
    const int g  = lane >> 2;   // group 0..15 (one node each)
    const int li = lane & 3;    // 8 cols (16B) per lane
    const int c0 = slice * 32 + li * 8;

    const int node = perm[ng * 64 + w * 16 + g];
    const bool act = node < N_NODES;

    int jb = 0, len = 0;
    if (act) {
        jb = row_beg[node];
        len = row_end[node] - jb;
    }
    // wave max of len (groups in a wave are degree-adjacent -> small waste)
    int ml = len;
    ml = max(ml, __shfl_xor(ml, 4));
    ml = max(ml, __shfl_xor(ml, 8));
    ml = max(ml, __shfl_xor(ml, 16));
    ml = max(ml, __shfl_xor(ml, 32));

    const int lenm1 = (len > 0) ? len - 1 : 0;
    const unsigned short* hb = h1b + c0;

    f32x2 a0 = {0.f, 0.f}, a1 = {0.f, 0.f}, a2 = {0.f, 0.f}, a3 = {0.f, 0.f};

    for (int i = 0; i < ml; i += 2) {
        int x0 = csr[jb + min(i, lenm1)];
        int x1 = csr[jb + min(i + 1, lenm1)];
        x0 = (i < len) ? x0 : ZROW;
        x1 = (i + 1 < len) ? x1 : ZROW;
        uint4 v0 = *(const uint4*)(hb + (size_t)x0 * HID_DIM);
        uint4 v1 = *(const uint4*)(hb + (size_t)x1 * HID_DIM);
        a0.x += bfl(v0.x); a0.y += bfh(v0.x);
        a1.x += bfl(v0.y); a1.y += bfh(v0.y);
        a2.x += bfl(v0.z); a2.y += bfh(v0.z);
        a3.x += bfl(v0.w); a3.y += bfh(v0.w);
        a0.x += bfl(v1.x); a0.y += bfh(v1.x);
        a1.x += bfl(v1.y); a1.y += bfh(v1.y);
        a2.x += bfl(v1.z); a2.y += bfh(v1.z);
        a3.x += bfl(v1.w); a3.y += bfh(v1.w);
    }

    if (act) {
        const float di = dinv[node];
        uint4 sv = *(const uint4*)(h1b + (size_t)node * HID_DIM + c0);
        float4 bA = *(const float4*)(b1 + c0);
        float4 bB = *(const float4*)(b1 + c0 + 4);
        float r0 = fmaxf(fmaf(di, a0.x + bfl(sv.x), bA.x), 0.f);
        float r1 = fmaxf(fmaf(di, a0.y + bfh(sv.x), bA.y), 0.f);
        float r2 = fmaxf(fmaf(di, a1.x + bfl(sv.y), bA.z), 0.f);
        float r3 = fmaxf(fmaf(di, a1.y + bfh(sv.y), bA.w), 0.f);
        float r4 = fmaxf(fmaf(di, a2.x + bfl(sv.z), bB.x), 0.f);
        float r5 = fmaxf(fmaf(di, a2.y + bfh(sv.z), bB.y), 0.f);
        float r6 = fmaxf(fmaf(di, a3.x + bfl(sv.w), bB.z), 0.f);
        float r7 = fmaxf(fmaf(di, a3.y + bfh(sv.w), bB.w), 0.f);
        uint4 o;
        o.x = f2bf(r0) | (f2bf(r1) << 16);
        o.y = f2bf(r2) | (f2bf(r3) << 16);
        o.z = f2bf(r4) | (f2bf(r5) << 16);
        o.w = f2bf(r6) | (f2bf(r7) << 16);
        *(uint4*)(h1a + (size_t)node * HID_DIM + c0) = o;
    }
}

// ---------------- GEMM2 (MFMA): h2b[N][40](bf16) = dinv * (h1a @ W2) ----------------
__global__ __launch_bounds__(256) void k_gemm2_mfma(const unsigned short* __restrict__ h1a,
                                                    const unsigned short* __restrict__ w2t,
                                                    const float* __restrict__ dinv,
                                                    unsigned short* __restrict__ h2b) {
    __shared__ unsigned short Bs[N2 * HID_DIM];  // 12 KB
    const int tid = threadIdx.x;
#pragma unroll
    for (int i = tid; i < N2 * HID_DIM / 8; i += 256) {
        int row = i >> 4, slot = i & 15;
        *(uint4*)(Bs + row * HID_DIM + (slot ^ (row & 7)) * 8) =
            *(const uint4*)(w2t + (size_t)row * HID_DIM + slot * 8);
    }
    __syncthreads();

    const int w    = tid >> 6;
    const int lane = tid & 63;
    const int r  = lane & 15;
    const int kg = lane >> 4;
    const int row0 = blockIdx.x * 64 + w * 16;

    bf16x8 bfr[4][3];
#pragma unroll
    for (int ks = 0; ks < 4; ++ks)
#pragma unroll
        for (int f = 0; f < 3; ++f) {
            int row = f * 16 + r;
            int slot = ks * 4 + kg;
            bfr[ks][f] = *(const bf16x8*)(Bs + row * HID_DIM + (slot ^ (row & 7)) * 8);
        }

    f32x4 acc[3] = {};
#pragma unroll
    for (int ks = 0; ks < 4; ++ks) {
        bf16x8 af = *(const bf16x8*)(h1a + (size_t)(row0 + r) * HID_DIM + ks * 32 + kg * 8);
#pragma unroll
        for (int f = 0; f < 3; ++f)
            acc[f] = __builtin_amdgcn_mfma_f32_16x16x32_bf16(af, bfr[ks][f], acc[f], 0, 0, 0);
    }

    float dv[4];
#pragma unroll
    for (int v = 0; v < 4; ++v) {
        int gr = row0 + kg * 4 + v;
        dv[v] = (gr < N_NODES) ? dinv[gr] : 0.f;
    }
#pragma unroll
    for (int f = 0; f < 3; ++f) {
        int col = f * 16 + r;
        if (col < OUT_DIM) {
#pragma unroll
            for (int v = 0; v < 4; ++v) {
                int gr = row0 + kg * 4 + v;
                if (gr < N_NODES)
                    h2b[(size_t)gr * H2S + col] = (unsigned short)f2bf(acc[f][v] * dv[v]);
            }
        }
    }
}

// ---------------- gather layer 2 (unmasked pure sum) + bias + log_softmax ----------------
__global__ __launch_bounds__(256) void k_gather2(const unsigned short* __restrict__ h2b,
                                                 const float* __restrict__ dinv,
                                                 const float* __restrict__ b2,
                                                 const int* __restrict__ row_beg,
                                                 const int* __restrict__ row_end,
                                                 const int* __restrict__ csr,
                                                 float* __restrict__ out) {
    const int node = blockIdx.x * 4 + (threadIdx.x >> 6);
    const int lane = threadIdx.x & 63;
    const bool act = lane < OUT_DIM;
    const float di = dinv[node];

    float a = bf2f(h2b[(size_t)node * H2S + lane]);

    int j = row_beg[node];
    const int je = row_end[node];
    for (; j + 16 <= je; j += 16) {
        int4 i0 = *(const int4*)(csr + j);
        int4 i1 = *(const int4*)(csr + j + 4);
        int4 i2 = *(const int4*)(csr + j + 8);
        int4 i3 = *(const int4*)(csr + j + 12);
        unsigned short hv[16];
        hv[0]  = h2b[(size_t)i0.x * H2S + lane];
        hv[1]  = h2b[(size_t)i0.y * H2S + lane];
        hv[2]  = h2b[(size_t)i0.z * H2S + lane];
        hv[3]  = h2b[(size_t)i0.w * H2S + lane];
        hv[4]  = h2b[(size_t)i1.x * H2S + lane];
        hv[5]  = h2b[(size_t)i1.y * H2S + lane];
        hv[6]  = h2b[(size_t)i1.z * H2S + lane];
        hv[7]  = h2b[(size_t)i1.w * H2S + lane];
        hv[8]  = h2b[(size_t)i2.x * H2S + lane];
        hv[9]  = h2b[(size_t)i2.y * H2S + lane];
        hv[10] = h2b[(size_t)i2.z * H2S + lane];
        hv[11] = h2b[(size_t)i2.w * H2S + lane];
        hv[12] = h2b[(size_t)i3.x * H2S + lane];
        hv[13] = h2b[(size_t)i3.y * H2S + lane];
        hv[14] = h2b[(size_t)i3.z * H2S + lane];
        hv[15] = h2b[(size_t)i3.w * H2S + lane];
#pragma unroll
        for (int uu = 0; uu < 16; ++uu) a += bf2f(hv[uu]);
    }
    if (j < je) {
        int4 i0 = *(const int4*)(csr + j);
        int4 i1 = *(const int4*)(csr + j + 4);
        unsigned short hv[8];
        hv[0] = h2b[(size_t)i0.x * H2S + lane];
        hv[1] = h2b[(size_t)i0.y * H2S + lane];
        hv[2] = h2b[(size_t)i0.z * H2S + lane];
        hv[3] = h2b[(size_t)i0.w * H2S + lane];
        hv[4] = h2b[(size_t)i1.x * H2S + lane];
        hv[5] = h2b[(size_t)i1.y * H2S + lane];
        hv[6] = h2b[(size_t)i1.z * H2S + lane];
        hv[7] = h2b[(size_t)i1.w * H2S + lane];
#pragma unroll
        for (int uu = 0; uu < 8; ++uu) a += bf2f(hv[uu]);
    }

    float v = act ? fmaf(di, a, b2[lane]) : -INFINITY;
    float m = v;
#pragma unroll
    for (int off = 32; off > 0; off >>= 1) m = fmaxf(m, __shfl_xor(m, off));
    float ex = act ? expf(v - m) : 0.f;
    float s = ex;
#pragma unroll
    for (int off = 32; off > 0; off >>= 1) s += __shfl_xor(s, off);
    float ls = logf(s);
    if (act) out[(long long)node * OUT_DIM + lane] = v - m - ls;
}

// ---------------- launch ----------------
extern "C" void kernel_launch(void* const* d_in, const int* in_sizes, int n_in,
                              void* d_out, int out_size, void* d_ws, size_t ws_size,
                              hipStream_t stream) {
    const float* x  = (const float*)d_in[0];
    const int*   ei = (const int*)d_in[1];
    const float* W1 = (const float*)d_in[2];
    const float* b1 = (const float*)d_in[3];
    const float* W2 = (const float*)d_in[4];
    const float* b2 = (const float*)d_in[5];
    float* out = (float*)d_out;

    const int* esrc = ei;
    const int* edst = ei + N_EDGES;

    char* w = (char*)d_ws;
    unsigned int* part = (unsigned int*)w;  w += sizeof(unsigned int) * (size_t)NB * BCAP;  // 8.0 MB
    int*    csr     = (int*)w;    w += sizeof(int) * (size_t)NB * SEGSTRIDE;  // 9.6 MB
    int*    row_beg = (int*)w;    w += sizeof(int) * NROWS;
    int*    row_end = (int*)w;    w += sizeof(int) * NROWS;
    float*  dinv    = (float*)w;  w += sizeof(float) * NROWS;
    int*    gcursor = (int*)w;    w += sizeof(int) * 256;
    int*    perm    = (int*)w;    w += sizeof(int) * NPERM;
    unsigned short* h1b = (unsigned short*)w;  w += sizeof(short) * (size_t)NROWS * HID_DIM;
    unsigned short* h1a = (unsigned short*)w;  w += sizeof(short) * (size_t)NROWS * HID_DIM;
    unsigned short* h2b = (unsigned short*)w;  w += sizeof(short) * (size_t)NROWS * H2S;
    unsigned short* w1t = (unsigned short*)w;  w += sizeof(short) * HID_DIM * IN_DIM;
    unsigned short* w2t = (unsigned short*)w;  w += sizeof(short) * N2 * HID_DIM;

    // prep (init + w1t + w2t fused)
    k_prep<<<1 + HID_DIM, 256, 0, stream>>>(W1, W2, gcursor, w1t, w2t, h1b, h2b);

    // CSR build (padded segments, fixed stride) + degree-sorted perm
    k_part<<<NPB, 256, 0, stream>>>(esrc, edst, gcursor, part);
    k_bucket<<<NB, 256, 0, stream>>>(part, gcursor, row_beg, row_end, dinv, csr, perm);

    // layer 1 GEMM via MFMA (pre-scaled by dinv), row-major h1b
    k_gemm1_mfma<<<NROWS / 128, 256, 0, stream>>>(x, w1t, dinv, h1b);

    // gather1 (+self+bias+ReLU) -> h1a: 782 node-groups x 4 slices, XCD-affine
    k_layer1<<<391 * 8, 256, 0, stream>>>(h1b, dinv, b1, row_beg, row_end, csr, perm, h1a);

    // GEMM2 via MFMA -> h2b (pre-scaled by dinv)
    k_gemm2_mfma<<<NROWS / 64, 256, 0, stream>>>(h1a, w2t, dinv, h2b);

    // gather2 + log_softmax
    k_gather2<<<N_NODES / 4, 256, 0, stream>>>(h2b, dinv, b2, row_beg, row_end, csr, out);
}

// Round 12
// 160.536 us; speedup vs baseline: 1.4843x; 1.4843x over previous
//
#include <hip/hip_runtime.h>
#include <math.h>

#define N_NODES 50000
#define N_EDGES 1600000
#define IN_DIM 256
#define HID_DIM 128
#define OUT_DIM 40
#define N2 48          // OUT_DIM padded to MFMA multiple
#define H2S 40         // h2b row stride (elems): 50048*40*2B = 4.0 MB -> L2 resident
#define ZROW N_NODES   // dedicated all-zero row index for CSR padding
#define NROWS 50048

#define NB 196         // dst buckets of 256 nodes
#define BCAP 10240     // part[] slots per bucket
#define SEGSTRIDE 12288
#define PCHUNK 4096
#define NPB ((N_EDGES + PCHUNK - 1) / PCHUNK)  // 391

typedef __attribute__((ext_vector_type(8))) short bf16x8;
typedef __attribute__((ext_vector_type(4))) float f32x4;
typedef __attribute__((ext_vector_type(2))) float f32x2;

// ---------------- bf16 helpers (RNE) ----------------
__device__ __forceinline__ unsigned int f2bf(float f) {
    unsigned int u = __float_as_uint(f);
    unsigned int r = u + 0x7FFFu + ((u >> 16) & 1u);
    return r >> 16;
}
__device__ __forceinline__ float bf2f(unsigned short s) {
    return __uint_as_float(((unsigned int)s) << 16);
}

// ---------------- prep: gcursor bases, zero rows, w1t, w2t ----------------
__global__ __launch_bounds__(256) void k_prep(const float* __restrict__ W1,
                                              const float* __restrict__ W2,
                                              int* __restrict__ gcursor,
                                              unsigned short* __restrict__ w1t,
                                              unsigned short* __restrict__ w2t,
                                              unsigned short* __restrict__ h1b,
                                              unsigned short* __restrict__ h2b) {
    const int b = blockIdx.x, t = threadIdx.x;
    if (b == 0) {
        if (t < NB) gcursor[t] = t * BCAP;
        if (t < HID_DIM) h1b[(size_t)ZROW * HID_DIM + t] = 0;
        if (t < H2S) h2b[(size_t)ZROW * H2S + t] = 0;
        for (int i = t; i < N2 * HID_DIM; i += 256) {
            int c = i >> 7, k = i & 127;
            w2t[i] = (c < OUT_DIM) ? (unsigned short)f2bf(W2[k * OUT_DIM + c]) : (unsigned short)0;
        }
    } else {
        int c = b - 1;
        w1t[c * IN_DIM + t] = (unsigned short)f2bf(W1[t * HID_DIM + c]);
    }
}

// ---------------- partition edges into 196 dst-buckets (4B packed) ----------------
__global__ __launch_bounds__(256) void k_part(const int* __restrict__ src,
                                              const int* __restrict__ dst,
                                              int* __restrict__ gcursor,
                                              unsigned int* __restrict__ part) {
    __shared__ int hist[NB];
    __shared__ int lcur[NB];
    const int tid = threadIdx.x;
    const int base = blockIdx.x * PCHUNK;
    const int n = min(PCHUNK, N_EDGES - base);

    for (int i = tid; i < NB; i += 256) hist[i] = 0;
    __syncthreads();
    for (int i = tid; i < n; i += 256)
        atomicAdd(&hist[dst[base + i] >> 8], 1);
    __syncthreads();
    for (int i = tid; i < NB; i += 256)
        lcur[i] = atomicAdd(&gcursor[i], hist[i]);
    __syncthreads();
    for (int i = tid; i < n; i += 256) {
        int d = dst[base + i];
        int g = d >> 8;
        int pos = atomicAdd(&lcur[g], 1);
        part[pos] = ((unsigned int)(d & 255) << 16) | (unsigned int)src[base + i];
    }
}

// ---------------- per-bucket counting sort: row_beg/row_end/dinv + padded csr ----------------
__global__ __launch_bounds__(256) void k_bucket(const unsigned int* __restrict__ part,
                                                const int* __restrict__ gcursor,
                                                int* __restrict__ row_beg,
                                                int* __restrict__ row_end,
                                                float* __restrict__ dinv,
                                                int* __restrict__ csr) {
    __shared__ int hist[256];
    __shared__ int sh[256];
    __shared__ int cur[256];
    const int g = blockIdx.x;
    const int tid = threadIdx.x;
    const int ebase = g * BCAP;
    const int ecnt = gcursor[g] - ebase;
    const int cbase = g * SEGSTRIDE;

    hist[tid] = 0;
    __syncthreads();
    for (int i = tid; i < ecnt; i += 256)
        atomicAdd(&hist[(part[ebase + i] >> 16) & 255], 1);
    __syncthreads();

    int own = hist[tid];
    int pcnt = (own + 7) & ~7;
    sh[tid] = pcnt;
    __syncthreads();
    for (int off = 1; off < 256; off <<= 1) {
        int t = (tid >= off) ? sh[tid - off] : 0;
        __syncthreads();
        sh[tid] += t;
        __syncthreads();
    }
    int pexcl = sh[tid] - pcnt;

    int node = (g << 8) + tid;
    if (node < N_NODES) {
        row_beg[node] = cbase + pexcl;
        row_end[node] = cbase + pexcl + pcnt;
        dinv[node] = rsqrtf((float)own + 1.0f);
    }
    cur[tid] = cbase + pexcl;
    for (int p = own; p < pcnt; ++p) csr[cbase + pexcl + p] = ZROW;
    __syncthreads();

    for (int i = tid; i < ecnt; i += 256) {
        unsigned int p = part[ebase + i];
        int pos = atomicAdd(&cur[(p >> 16) & 255], 1);
        csr[pos] = (int)(p & 0xFFFFu);
    }
}

// ---------------- GEMM1 (MFMA): h1b[N][128](bf16) = dinv * (x @ W1), 64-row tile ----------------
__global__ __launch_bounds__(256) void k_gemm1_mfma(const float* __restrict__ x,
                                                    const unsigned short* __restrict__ w1t,
                                                    const float* __restrict__ dinv,
                                                    unsigned short* __restrict__ h1b) {
    __shared__ unsigned short Asub[64 * 32];
    __shared__ unsigned short Bsub[128 * 32];
    const int tid  = threadIdx.x;
    const int w    = tid >> 6;
    const int lane = tid & 63;
    const int row0 = blockIdx.x * 64;
    const int r  = lane & 15;
    const int kg = lane >> 4;

    f32x4 acc[8] = {};

    for (int k0 = 0; k0 < IN_DIM; k0 += 32) {
        {
            int ar = tid >> 2, as = tid & 3;
            int asw = as ^ (ar & 3);
            uint4 pk = make_uint4(0, 0, 0, 0);
            int grow = row0 + ar;
            if (grow < N_NODES) {
                const float4* p = (const float4*)(x + (size_t)grow * IN_DIM + k0 + as * 8);
                float4 v0 = p[0], v1 = p[1];
                pk.x = f2bf(v0.x) | (f2bf(v0.y) << 16);
                pk.y = f2bf(v0.z) | (f2bf(v0.w) << 16);
                pk.z = f2bf(v1.x) | (f2bf(v1.y) << 16);
                pk.w = f2bf(v1.z) | (f2bf(v1.w) << 16);
            }
            *(uint4*)(Asub + ar * 32 + asw * 8) = pk;
        }
#pragma unroll
        for (int i = 0; i < 2; ++i) {
            int q = tid + i * 256;
            int col = q >> 2, slot = q & 3;
            int sl2 = slot ^ (col & 3);
            *(uint4*)(Bsub + col * 32 + sl2 * 8) =
                *(const uint4*)(w1t + (size_t)col * IN_DIM + k0 + slot * 8);
        }
        __syncthreads();

        bf16x8 af = *(const bf16x8*)(Asub + (w * 16 + r) * 32 + ((kg ^ (r & 3)) * 8));
#pragma unroll
        for (int f = 0; f < 8; ++f) {
            bf16x8 bfr = *(const bf16x8*)(Bsub + (f * 16 + r) * 32 + ((kg ^ (r & 3)) * 8));
            acc[f] = __builtin_amdgcn_mfma_f32_16x16x32_bf16(af, bfr, acc[f], 0, 0, 0);
        }
        __syncthreads();
    }

    float dv[4];
#pragma unroll
    for (int v = 0; v < 4; ++v) {
        int gr = row0 + w * 16 + kg * 4 + v;
        dv[v] = (gr < N_NODES) ? dinv[gr] : 0.f;
    }
#pragma unroll
    for (int f = 0; f < 8; ++f)
#pragma unroll
        for (int v = 0; v < 4; ++v) {
            int gr = row0 + w * 16 + kg * 4 + v;
            if (gr < N_NODES)
                h1b[(size_t)gr * HID_DIM + f * 16 + r] = (unsigned short)f2bf(acc[f][v] * dv[v]);
        }
}

// ---------------- layer-1 gather (round-8 proven form): h1a = relu(di*sum + b1) ----------------
__global__ __launch_bounds__(256) void k_layer1(const unsigned short* __restrict__ h1b,
                                                const float* __restrict__ dinv,
                                                const float* __restrict__ b1,
                                                const int* __restrict__ row_beg,
                                                const int* __restrict__ row_end,
                                                const int* __restrict__ csr,
                                                unsigned short* __restrict__ h1a) {
    const int w    = threadIdx.x >> 6;
    const int lane = threadIdx.x & 63;
    const int c0   = lane * 2;
    const float bb0 = b1[c0], bb1 = b1[c0 + 1];

    const int node = blockIdx.x * 4 + w;
    const float di = dinv[node];

    unsigned int us = *(const unsigned int*)(h1b + (size_t)node * HID_DIM + c0);
    f32x2 acc;
    acc.x = bf2f((unsigned short)us);
    acc.y = bf2f((unsigned short)(us >> 16));

    int j = row_beg[node];
    const int je = row_end[node];
    for (; j + 16 <= je; j += 16) {
        int4 i0 = *(const int4*)(csr + j);
        int4 i1 = *(const int4*)(csr + j + 4);
        int4 i2 = *(const int4*)(csr + j + 8);
        int4 i3 = *(const int4*)(csr + j + 12);
        unsigned int uu[16];
        uu[0]  = *(const unsigned int*)(h1b + (size_t)i0.x * HID_DIM + c0);
        uu[1]  = *(const unsigned int*)(h1b + (size_t)i0.y * HID_DIM + c0);
        uu[2]  = *(const unsigned int*)(h1b + (size_t)i0.z * HID_DIM + c0);
        uu[3]  = *(const unsigned int*)(h1b + (size_t)i0.w * HID_DIM + c0);
        uu[4]  = *(const unsigned int*)(h1b + (size_t)i1.x * HID_DIM + c0);
        uu[5]  = *(const unsigned int*)(h1b + (size_t)i1.y * HID_DIM + c0);
        uu[6]  = *(const unsigned int*)(h1b + (size_t)i1.z * HID_DIM + c0);
        uu[7]  = *(const unsigned int*)(h1b + (size_t)i1.w * HID_DIM + c0);
        uu[8]  = *(const unsigned int*)(h1b + (size_t)i2.x * HID_DIM + c0);
        uu[9]  = *(const unsigned int*)(h1b + (size_t)i2.y * HID_DIM + c0);
        uu[10] = *(const unsigned int*)(h1b + (size_t)i2.z * HID_DIM + c0);
        uu[11] = *(const unsigned int*)(h1b + (size_t)i2.w * HID_DIM + c0);
        uu[12] = *(const unsigned int*)(h1b + (size_t)i3.x * HID_DIM + c0);
        uu[13] = *(const unsigned int*)(h1b + (size_t)i3.y * HID_DIM + c0);
        uu[14] = *(const unsigned int*)(h1b + (size_t)i3.z * HID_DIM + c0);
        uu[15] = *(const unsigned int*)(h1b + (size_t)i3.w * HID_DIM + c0);
#pragma unroll
        for (int u = 0; u < 16; ++u) {
            f32x2 t;
            t.x = __uint_as_float(uu[u] << 16);
            t.y = __uint_as_float(uu[u] & 0xffff0000u);
            acc += t;
        }
    }
    if (j < je) {  // exactly one 8-batch remains
        int4 i0 = *(const int4*)(csr + j);
        int4 i1 = *(const int4*)(csr + j + 4);
        unsigned int uu[8];
        uu[0] = *(const unsigned int*)(h1b + (size_t)i0.x * HID_DIM + c0);
        uu[1] = *(const unsigned int*)(h1b + (size_t)i0.y * HID_DIM + c0);
        uu[2] = *(const unsigned int*)(h1b + (size_t)i0.z * HID_DIM + c0);
        uu[3] = *(const unsigned int*)(h1b + (size_t)i0.w * HID_DIM + c0);
        uu[4] = *(const unsigned int*)(h1b + (size_t)i1.x * HID_DIM + c0);
        uu[5] = *(const unsigned int*)(h1b + (size_t)i1.y * HID_DIM + c0);
        uu[6] = *(const unsigned int*)(h1b + (size_t)i1.z * HID_DIM + c0);
        uu[7] = *(const unsigned int*)(h1b + (size_t)i1.w * HID_DIM + c0);
#pragma unroll
        for (int u = 0; u < 8; ++u) {
            f32x2 t;
            t.x = __uint_as_float(uu[u] << 16);
            t.y = __uint_as_float(uu[u] & 0xffff0000u);
            acc += t;
        }
    }

    float r0 = fmaxf(fmaf(di, acc.x, bb0), 0.f);
    float r1 = fmaxf(fmaf(di, acc.y, bb1), 0.f);
    *(unsigned int*)(h1a + (size_t)node * HID_DIM + c0) = f2bf(r0) | (f2bf(r1) << 16);
}

// ---------------- GEMM2 (MFMA): h2b[N][40](bf16) = dinv * (h1a @ W2) ----------------
__global__ __launch_bounds__(256) void k_gemm2_mfma(const unsigned short* __restrict__ h1a,
                                                    const unsigned short* __restrict__ w2t,
                                                    const float* __restrict__ dinv,
                                                    unsigned short* __restrict__ h2b) {
    __shared__ unsigned short Bs[N2 * HID_DIM];  // 12 KB
    const int tid = threadIdx.x;
#pragma unroll
    for (int i = tid; i < N2 * HID_DIM / 8; i += 256) {
        int row = i >> 4, slot = i & 15;
        *(uint4*)(Bs + row * HID_DIM + (slot ^ (row & 7)) * 8) =
            *(const uint4*)(w2t + (size_t)row * HID_DIM + slot * 8);
    }
    __syncthreads();

    const int w    = tid >> 6;
    const int lane = tid & 63;
    const int r  = lane & 15;
    const int kg = lane >> 4;
    const int row0 = blockIdx.x * 64 + w * 16;

    bf16x8 bfr[4][3];
#pragma unroll
    for (int ks = 0; ks < 4; ++ks)
#pragma unroll
        for (int f = 0; f < 3; ++f) {
            int row = f * 16 + r;
            int slot = ks * 4 + kg;
            bfr[ks][f] = *(const bf16x8*)(Bs + row * HID_DIM + (slot ^ (row & 7)) * 8);
        }

    f32x4 acc[3] = {};
#pragma unroll
    for (int ks = 0; ks < 4; ++ks) {
        bf16x8 af = *(const bf16x8*)(h1a + (size_t)(row0 + r) * HID_DIM + ks * 32 + kg * 8);
#pragma unroll
        for (int f = 0; f < 3; ++f)
            acc[f] = __builtin_amdgcn_mfma_f32_16x16x32_bf16(af, bfr[ks][f], acc[f], 0, 0, 0);
    }

    float dv[4];
#pragma unroll
    for (int v = 0; v < 4; ++v) {
        int gr = row0 + kg * 4 + v;
        dv[v] = (gr < N_NODES) ? dinv[gr] : 0.f;
    }
#pragma unroll
    for (int f = 0; f < 3; ++f) {
        int col = f * 16 + r;
        if (col < OUT_DIM) {
#pragma unroll
            for (int v = 0; v < 4; ++v) {
                int gr = row0 + kg * 4 + v;
                if (gr < N_NODES)
                    h2b[(size_t)gr * H2S + col] = (unsigned short)f2bf(acc[f][v] * dv[v]);
            }
        }
    }
}

// ---------------- gather layer 2 (unmasked pure sum) + bias + log_softmax ----------------
__global__ __launch_bounds__(256) void k_gather2(const unsigned short* __restrict__ h2b,
                                                 const float* __restrict__ dinv,
                                                 const float* __restrict__ b2,
                                                 const int* __restrict__ row_beg,
                                                 const int* __restrict__ row_end,
                                                 const int* __restrict__ csr,
                                                 float* __restrict__ out) {
    const int node = blockIdx.x * 4 + (threadIdx.x >> 6);
    const int lane = threadIdx.x & 63;
    const bool act = lane < OUT_DIM;
    const float di = dinv[node];

    float a = bf2f(h2b[(size_t)node * H2S + lane]);  // pad lanes read in-bounds garbage; masked below

    int j = row_beg[node];
    const int je = row_end[node];
    for (; j + 16 <= je; j += 16) {
        int4 i0 = *(const int4*)(csr + j);
        int4 i1 = *(const int4*)(csr + j + 4);
        int4 i2 = *(const int4*)(csr + j + 8);
        int4 i3 = *(const int4*)(csr + j + 12);
        unsigned short hv[16];
        hv[0]  = h2b[(size_t)i0.x * H2S + lane];
        hv[1]  = h2b[(size_t)i0.y * H2S + lane];
        hv[2]  = h2b[(size_t)i0.z * H2S + lane];
        hv[3]  = h2b[(size_t)i0.w * H2S + lane];
        hv[4]  = h2b[(size_t)i1.x * H2S + lane];
        hv[5]  = h2b[(size_t)i1.y * H2S + lane];
        hv[6]  = h2b[(size_t)i1.z * H2S + lane];
        hv[7]  = h2b[(size_t)i1.w * H2S + lane];
        hv[8]  = h2b[(size_t)i2.x * H2S + lane];
        hv[9]  = h2b[(size_t)i2.y * H2S + lane];
        hv[10] = h2b[(size_t)i2.z * H2S + lane];
        hv[11] = h2b[(size_t)i2.w * H2S + lane];
        hv[12] = h2b[(size_t)i3.x * H2S + lane];
        hv[13] = h2b[(size_t)i3.y * H2S + lane];
        hv[14] = h2b[(size_t)i3.z * H2S + lane];
        hv[15] = h2b[(size_t)i3.w * H2S + lane];
#pragma unroll
        for (int u = 0; u < 16; ++u) a += bf2f(hv[u]);
    }
    if (j < je) {
        int4 i0 = *(const int4*)(csr + j);
        int4 i1 = *(const int4*)(csr + j + 4);
        unsigned short hv[8];
        hv[0] = h2b[(size_t)i0.x * H2S + lane];
        hv[1] = h2b[(size_t)i0.y * H2S + lane];
        hv[2] = h2b[(size_t)i0.z * H2S + lane];
        hv[3] = h2b[(size_t)i0.w * H2S + lane];
        hv[4] = h2b[(size_t)i1.x * H2S + lane];
        hv[5] = h2b[(size_t)i1.y * H2S + lane];
        hv[6] = h2b[(size_t)i1.z * H2S + lane];
        hv[7] = h2b[(size_t)i1.w * H2S + lane];
#pragma unroll
        for (int u = 0; u < 8; ++u) a += bf2f(hv[u]);
    }

    float v = act ? fmaf(di, a, b2[lane]) : -INFINITY;
    float m = v;
#pragma unroll
    for (int off = 32; off > 0; off >>= 1) m = fmaxf(m, __shfl_xor(m, off));
    float ex = act ? expf(v - m) : 0.f;
    float s = ex;
#pragma unroll
    for (int off = 32; off > 0; off >>= 1) s += __shfl_xor(s, off);
    float ls = logf(s);
    if (act) out[(long long)node * OUT_DIM + lane] = v - m - ls;
}

// ---------------- launch ----------------
extern "C" void kernel_launch(void* const* d_in, const int* in_sizes, int n_in,
                              void* d_out, int out_size, void* d_ws, size_t ws_size,
                              hipStream_t stream) {
    const float* x  = (const float*)d_in[0];
    const int*   ei = (const int*)d_in[1];
    const float* W1 = (const float*)d_in[2];
    const float* b1 = (const float*)d_in[3];
    const float* W2 = (const float*)d_in[4];
    const float* b2 = (const float*)d_in[5];
    float* out = (float*)d_out;

    const int* esrc = ei;
    const int* edst = ei + N_EDGES;

    char* w = (char*)d_ws;
    unsigned int* part = (unsigned int*)w;  w += sizeof(unsigned int) * (size_t)NB * BCAP;  // 8.0 MB
    int*    csr     = (int*)w;    w += sizeof(int) * (size_t)NB * SEGSTRIDE;  // 9.6 MB
    int*    row_beg = (int*)w;    w += sizeof(int) * NROWS;
    int*    row_end = (int*)w;    w += sizeof(int) * NROWS;
    float*  dinv    = (float*)w;  w += sizeof(float) * NROWS;
    int*    gcursor = (int*)w;    w += sizeof(int) * 256;
    unsigned short* h1b = (unsigned short*)w;  w += sizeof(short) * (size_t)NROWS * HID_DIM;
    unsigned short* h1a = (unsigned short*)w;  w += sizeof(short) * (size_t)NROWS * HID_DIM;
    unsigned short* h2b = (unsigned short*)w;  w += sizeof(short) * (size_t)NROWS * H2S;
    unsigned short* w1t = (unsigned short*)w;  w += sizeof(short) * HID_DIM * IN_DIM;
    unsigned short* w2t = (unsigned short*)w;  w += sizeof(short) * N2 * HID_DIM;

    // prep (init + w1t + w2t fused)
    k_prep<<<1 + HID_DIM, 256, 0, stream>>>(W1, W2, gcursor, w1t, w2t, h1b, h2b);

    // CSR build (padded segments, fixed stride), 391-block partition
    k_part<<<NPB, 256, 0, stream>>>(esrc, edst, gcursor, part);
    k_bucket<<<NB, 256, 0, stream>>>(part, gcursor, row_beg, row_end, dinv, csr);

    // layer 1 GEMM via MFMA (pre-scaled by dinv), 64-row tiles
    k_gemm1_mfma<<<(N_NODES + 63) / 64, 256, 0, stream>>>(x, w1t, dinv, h1b);

    // gather1 (+self+bias+ReLU) -> h1a (round-8 proven form)
    k_layer1<<<N_NODES / 4, 256, 0, stream>>>(h1b, dinv, b1, row_beg, row_end, csr, h1a);

    // GEMM2 via MFMA -> h2b (pre-scaled by dinv)
    k_gemm2_mfma<<<NROWS / 64, 256, 0, stream>>>(h1a, w2t, dinv, h2b);

    // gather2 + log_softmax
    k_gather2<<<N_NODES / 4, 256, 0, stream>>>(h2b, dinv, b2, row_beg, row_end, csr, out);
}

// Round 13
// 160.377 us; speedup vs baseline: 1.4858x; 1.0010x over previous
//
#include <hip/hip_runtime.h>
#include <math.h>

#define N_NODES 50000
#define N_EDGES 1600000
#define IN_DIM 256
#define HID_DIM 128
#define OUT_DIM 40
#define N2 48          // OUT_DIM padded to MFMA multiple
#define H2S 40         // h2b row stride (elems): 4.0 MB -> L2 resident
#define ZROW N_NODES   // dedicated all-zero row index for CSR padding
#define NROWS 50048    // h1b/h1a/h2b row allocation
#define NALLOC 50176   // row_beg/row_end/dinv allocation (196*256)

#define NB 196         // dst buckets of 256 nodes
#define BCAP 10240     // part[] slots per bucket
#define SEGSTRIDE 12288
#define PCHUNK 4096
#define NPB ((N_EDGES + PCHUNK - 1) / PCHUNK)  // 391

typedef __attribute__((ext_vector_type(8))) short bf16x8;
typedef __attribute__((ext_vector_type(4))) float f32x4;
typedef __attribute__((ext_vector_type(2))) float f32x2;

// ---------------- bf16 helpers (RNE) ----------------
__device__ __forceinline__ unsigned int f2bf(float f) {
    unsigned int u = __float_as_uint(f);
    unsigned int r = u + 0x7FFFu + ((u >> 16) & 1u);
    return r >> 16;
}
__device__ __forceinline__ float bfl(unsigned int u) { return __uint_as_float(u << 16); }
__device__ __forceinline__ float bfh(unsigned int u) { return __uint_as_float(u & 0xffff0000u); }
__device__ __forceinline__ float bf2f(unsigned short s) {
    return __uint_as_float(((unsigned int)s) << 16);
}

// ---------------- prep: gcursor bases, zero rows (all 4 slices), w1t, w2t ----------------
__global__ __launch_bounds__(256) void k_prep(const float* __restrict__ W1,
                                              const float* __restrict__ W2,
                                              int* __restrict__ gcursor,
                                              unsigned short* __restrict__ w1t,
                                              unsigned short* __restrict__ w2t,
                                              unsigned short* __restrict__ h1b,
                                              unsigned short* __restrict__ h2b) {
    const int b = blockIdx.x, t = threadIdx.x;
    if (b == 0) {
        if (t < NB) gcursor[t] = t * BCAP;
        if (t < 128) {  // zero ZROW row in all 4 h1b slices
            int s = t >> 5, c = t & 31;
            h1b[((size_t)s * NROWS + ZROW) * 32 + c] = 0;
        }
        if (t < H2S) h2b[(size_t)ZROW * H2S + t] = 0;
        for (int i = t; i < N2 * HID_DIM; i += 256) {
            int c = i >> 7, k = i & 127;
            w2t[i] = (c < OUT_DIM) ? (unsigned short)f2bf(W2[k * OUT_DIM + c]) : (unsigned short)0;
        }
    } else {
        int c = b - 1;
        w1t[c * IN_DIM + t] = (unsigned short)f2bf(W1[t * HID_DIM + c]);
    }
}

// ---------------- partition edges into 196 dst-buckets (4B packed) ----------------
__global__ __launch_bounds__(256) void k_part(const int* __restrict__ src,
                                              const int* __restrict__ dst,
                                              int* __restrict__ gcursor,
                                              unsigned int* __restrict__ part) {
    __shared__ int hist[NB];
    __shared__ int lcur[NB];
    const int tid = threadIdx.x;
    const int base = blockIdx.x * PCHUNK;
    const int n = min(PCHUNK, N_EDGES - base);

    for (int i = tid; i < NB; i += 256) hist[i] = 0;
    __syncthreads();
    for (int i = tid; i < n; i += 256)
        atomicAdd(&hist[dst[base + i] >> 8], 1);
    __syncthreads();
    for (int i = tid; i < NB; i += 256)
        lcur[i] = atomicAdd(&gcursor[i], hist[i]);
    __syncthreads();
    for (int i = tid; i < n; i += 256) {
        int d = dst[base + i];
        int g = d >> 8;
        int pos = atomicAdd(&lcur[g], 1);
        part[pos] = ((unsigned int)(d & 255) << 16) | (unsigned int)src[base + i];
    }
}

// ---------------- per-bucket counting sort: row_beg/row_end/dinv + padded csr ----------------
__global__ __launch_bounds__(256) void k_bucket(const unsigned int* __restrict__ part,
                                                const int* __restrict__ gcursor,
                                                int* __restrict__ row_beg,
                                                int* __restrict__ row_end,
                                                float* __restrict__ dinv,
                                                int* __restrict__ csr) {
    __shared__ int hist[256];
    __shared__ int sh[256];
    __shared__ int cur[256];
    const int g = blockIdx.x;
    const int tid = threadIdx.x;
    const int ebase = g * BCAP;
    const int ecnt = gcursor[g] - ebase;
    const int cbase = g * SEGSTRIDE;

    hist[tid] = 0;
    __syncthreads();
    for (int i = tid; i < ecnt; i += 256)
        atomicAdd(&hist[(part[ebase + i] >> 16) & 255], 1);
    __syncthreads();

    int own = hist[tid];
    int pcnt = (own + 7) & ~7;
    sh[tid] = pcnt;
    __syncthreads();
    for (int off = 1; off < 256; off <<= 1) {
        int t = (tid >= off) ? sh[tid - off] : 0;
        __syncthreads();
        sh[tid] += t;
        __syncthreads();
    }
    int pexcl = sh[tid] - pcnt;

    // write for ALL 50176 slots (nodes >= N_NODES get empty ranges)
    int node = (g << 8) + tid;
    row_beg[node] = cbase + pexcl;
    row_end[node] = cbase + pexcl + pcnt;
    dinv[node] = rsqrtf((float)own + 1.0f);
    cur[tid] = cbase + pexcl;
    for (int p = own; p < pcnt; ++p) csr[cbase + pexcl + p] = ZROW;
    __syncthreads();

    for (int i = tid; i < ecnt; i += 256) {
        unsigned int p = part[ebase + i];
        int pos = atomicAdd(&cur[(p >> 16) & 255], 1);
        csr[pos] = (int)(p & 0xFFFFu);
    }
}

// ---------------- GEMM1 (MFMA): h1b[4][N][32](bf16 slices) = dinv * (x @ W1) ----------------
__global__ __launch_bounds__(256) void k_gemm1_mfma(const float* __restrict__ x,
                                                    const unsigned short* __restrict__ w1t,
                                                    const float* __restrict__ dinv,
                                                    unsigned short* __restrict__ h1b) {
    __shared__ unsigned short Asub[64 * 32];
    __shared__ unsigned short Bsub[128 * 32];
    const int tid  = threadIdx.x;
    const int w    = tid >> 6;
    const int lane = tid & 63;
    const int row0 = blockIdx.x * 64;
    const int r  = lane & 15;
    const int kg = lane >> 4;

    f32x4 acc[8] = {};

    for (int k0 = 0; k0 < IN_DIM; k0 += 32) {
        {
            int ar = tid >> 2, as = tid & 3;
            int asw = as ^ (ar & 3);
            uint4 pk = make_uint4(0, 0, 0, 0);
            int grow = row0 + ar;
            if (grow < N_NODES) {
                const float4* p = (const float4*)(x + (size_t)grow * IN_DIM + k0 + as * 8);
                float4 v0 = p[0], v1 = p[1];
                pk.x = f2bf(v0.x) | (f2bf(v0.y) << 16);
                pk.y = f2bf(v0.z) | (f2bf(v0.w) << 16);
                pk.z = f2bf(v1.x) | (f2bf(v1.y) << 16);
                pk.w = f2bf(v1.z) | (f2bf(v1.w) << 16);
            }
            *(uint4*)(Asub + ar * 32 + asw * 8) = pk;
        }
#pragma unroll
        for (int i = 0; i < 2; ++i) {
            int q = tid + i * 256;
            int col = q >> 2, slot = q & 3;
            int sl2 = slot ^ (col & 3);
            *(uint4*)(Bsub + col * 32 + sl2 * 8) =
                *(const uint4*)(w1t + (size_t)col * IN_DIM + k0 + slot * 8);
        }
        __syncthreads();

        bf16x8 af = *(const bf16x8*)(Asub + (w * 16 + r) * 32 + ((kg ^ (r & 3)) * 8));
#pragma unroll
        for (int f = 0; f < 8; ++f) {
            bf16x8 bfr = *(const bf16x8*)(Bsub + (f * 16 + r) * 32 + ((kg ^ (r & 3)) * 8));
            acc[f] = __builtin_amdgcn_mfma_f32_16x16x32_bf16(af, bfr, acc[f], 0, 0, 0);
        }
        __syncthreads();
    }

    float dv[4];
#pragma unroll
    for (int v = 0; v < 4; ++v) {
        int gr = row0 + w * 16 + kg * 4 + v;
        dv[v] = (gr < N_NODES) ? dinv[gr] : 0.f;
    }
    // D: row = w*16+kg*4+v, col = f*16+r -> slice f>>1, in-slice col (f&1)*16+r
#pragma unroll
    for (int f = 0; f < 8; ++f)
#pragma unroll
        for (int v = 0; v < 4; ++v) {
            int gr = row0 + w * 16 + kg * 4 + v;
            if (gr < N_NODES)
                h1b[((size_t)(f >> 1) * NROWS + gr) * 32 + (f & 1) * 16 + r] =
                    (unsigned short)f2bf(acc[f][v] * dv[v]);
        }
}

// ---------------- layer-1 gather: sliced layout + round-8 instruction economy ----------------
// blockIdx&7 -> slice = u>>1 (XCD-pair affine, 3.2MB slice L2-resident).
// Wave: 4 nodes (16 lanes each); per iter: 2 int4 csr loads + 8 uint gathers
// (each gather instr = 64 lanes x 4B = 256B payload) + 8 pk-adds. Exact per-group
// bounds via exec-mask divergence (len % 8 == 0 -> no masking instructions).
__global__ __launch_bounds__(256) void k_layer1(const unsigned short* __restrict__ h1b,
                                                const float* __restrict__ dinv,
                                                const float* __restrict__ b1,
                                                const int* __restrict__ row_beg,
                                                const int* __restrict__ row_end,
                                                const int* __restrict__ csr,
                                                unsigned short* __restrict__ h1a) {
    const int tid  = threadIdx.x;
    const int u     = blockIdx.x & 7;
    const int slice = u >> 1;
    const int nb    = ((blockIdx.x >> 3) << 1) | (u & 1);  // 0..3125
    const int w    = tid >> 6;
    const int lane = tid & 63;
    const int g  = lane >> 4;   // node within the wave's quad
    const int li = lane & 15;   // col-pair within slice

    const int node = nb * 16 + w * 4 + g;
    const unsigned short* hsl = h1b + (size_t)slice * NROWS * 32;

    int j = row_beg[node];
    const int je = row_end[node];

    f32x2 acc = {0.f, 0.f};
    while (j < je) {
        int4 i0 = *(const int4*)(csr + j);
        int4 i1 = *(const int4*)(csr + j + 4);
        unsigned int u0 = *(const unsigned int*)(hsl + (size_t)i0.x * 32 + li * 2);
        unsigned int u1 = *(const unsigned int*)(hsl + (size_t)i0.y * 32 + li * 2);
        unsigned int u2 = *(const unsigned int*)(hsl + (size_t)i0.z * 32 + li * 2);
        unsigned int u3 = *(const unsigned int*)(hsl + (size_t)i0.w * 32 + li * 2);
        unsigned int u4 = *(const unsigned int*)(hsl + (size_t)i1.x * 32 + li * 2);
        unsigned int u5 = *(const unsigned int*)(hsl + (size_t)i1.y * 32 + li * 2);
        unsigned int u6 = *(const unsigned int*)(hsl + (size_t)i1.z * 32 + li * 2);
        unsigned int u7 = *(const unsigned int*)(hsl + (size_t)i1.w * 32 + li * 2);
        f32x2 t;
        t.x = bfl(u0); t.y = bfh(u0); acc += t;
        t.x = bfl(u1); t.y = bfh(u1); acc += t;
        t.x = bfl(u2); t.y = bfh(u2); acc += t;
        t.x = bfl(u3); t.y = bfh(u3); acc += t;
        t.x = bfl(u4); t.y = bfh(u4); acc += t;
        t.x = bfl(u5); t.y = bfh(u5); acc += t;
        t.x = bfl(u6); t.y = bfh(u6); acc += t;
        t.x = bfl(u7); t.y = bfh(u7); acc += t;
        j += 8;
    }

    if (node < N_NODES) {
        const float di = dinv[node];
        unsigned int sv = *(const unsigned int*)(hsl + (size_t)node * 32 + li * 2);
        const int c = slice * 32 + li * 2;
        float2 bb = *(const float2*)(b1 + c);
        float r0 = fmaxf(fmaf(di, acc.x + bfl(sv), bb.x), 0.f);
        float r1 = fmaxf(fmaf(di, acc.y + bfh(sv), bb.y), 0.f);
        *(unsigned int*)(h1a + (size_t)node * HID_DIM + c) = f2bf(r0) | (f2bf(r1) << 16);
    }
}

// ---------------- GEMM2 (MFMA): h2b[N][40](bf16) = dinv * (h1a @ W2) ----------------
__global__ __launch_bounds__(256) void k_gemm2_mfma(const unsigned short* __restrict__ h1a,
                                                    const unsigned short* __restrict__ w2t,
                                                    const float* __restrict__ dinv,
                                                    unsigned short* __restrict__ h2b) {
    __shared__ unsigned short Bs[N2 * HID_DIM];  // 12 KB
    const int tid = threadIdx.x;
#pragma unroll
    for (int i = tid; i < N2 * HID_DIM / 8; i += 256) {
        int row = i >> 4, slot = i & 15;
        *(uint4*)(Bs + row * HID_DIM + (slot ^ (row & 7)) * 8) =
            *(const uint4*)(w2t + (size_t)row * HID_DIM + slot * 8);
    }
    __syncthreads();

    const int w    = tid >> 6;
    const int lane = tid & 63;
    const int r  = lane & 15;
    const int kg = lane >> 4;
    const int row0 = blockIdx.x * 64 + w * 16;

    bf16x8 bfr[4][3];
#pragma unroll
    for (int ks = 0; ks < 4; ++ks)
#pragma unroll
        for (int f = 0; f < 3; ++f) {
            int row = f * 16 + r;
            int slot = ks * 4 + kg;
            bfr[ks][f] = *(const bf16x8*)(Bs + row * HID_DIM + (slot ^ (row & 7)) * 8);
        }

    f32x4 acc[3] = {};
#pragma unroll
    for (int ks = 0; ks < 4; ++ks) {
        bf16x8 af = *(const bf16x8*)(h1a + (size_t)(row0 + r) * HID_DIM + ks * 32 + kg * 8);
#pragma unroll
        for (int f = 0; f < 3; ++f)
            acc[f] = __builtin_amdgcn_mfma_f32_16x16x32_bf16(af, bfr[ks][f], acc[f], 0, 0, 0);
    }

    float dv[4];
#pragma unroll
    for (int v = 0; v < 4; ++v) {
        int gr = row0 + kg * 4 + v;
        dv[v] = (gr < N_NODES) ? dinv[gr] : 0.f;
    }
#pragma unroll
    for (int f = 0; f < 3; ++f) {
        int col = f * 16 + r;
        if (col < OUT_DIM) {
#pragma unroll
            for (int v = 0; v < 4; ++v) {
                int gr = row0 + kg * 4 + v;
                if (gr < N_NODES)
                    h2b[(size_t)gr * H2S + col] = (unsigned short)f2bf(acc[f][v] * dv[v]);
            }
        }
    }
}

// ---------------- gather layer 2 (unmasked pure sum) + bias + log_softmax ----------------
__global__ __launch_bounds__(256) void k_gather2(const unsigned short* __restrict__ h2b,
                                                 const float* __restrict__ dinv,
                                                 const float* __restrict__ b2,
                                                 const int* __restrict__ row_beg,
                                                 const int* __restrict__ row_end,
                                                 const int* __restrict__ csr,
                                                 float* __restrict__ out) {
    const int node = blockIdx.x * 4 + (threadIdx.x >> 6);
    const int lane = threadIdx.x & 63;
    const bool act = lane < OUT_DIM;
    const float di = dinv[node];

    float a = bf2f(h2b[(size_t)node * H2S + lane]);  // pad lanes read in-bounds garbage; masked below

    int j = row_beg[node];
    const int je = row_end[node];
    for (; j + 16 <= je; j += 16) {
        int4 i0 = *(const int4*)(csr + j);
        int4 i1 = *(const int4*)(csr + j + 4);
        int4 i2 = *(const int4*)(csr + j + 8);
        int4 i3 = *(const int4*)(csr + j + 12);
        unsigned short hv[16];
        hv[0]  = h2b[(size_t)i0.x * H2S + lane];
        hv[1]  = h2b[(size_t)i0.y * H2S + lane];
        hv[2]  = h2b[(size_t)i0.z * H2S + lane];
        hv[3]  = h2b[(size_t)i0.w * H2S + lane];
        hv[4]  = h2b[(size_t)i1.x * H2S + lane];
        hv[5]  = h2b[(size_t)i1.y * H2S + lane];
        hv[6]  = h2b[(size_t)i1.z * H2S + lane];
        hv[7]  = h2b[(size_t)i1.w * H2S + lane];
        hv[8]  = h2b[(size_t)i2.x * H2S + lane];
        hv[9]  = h2b[(size_t)i2.y * H2S + lane];
        hv[10] = h2b[(size_t)i2.z * H2S + lane];
        hv[11] = h2b[(size_t)i2.w * H2S + lane];
        hv[12] = h2b[(size_t)i3.x * H2S + lane];
        hv[13] = h2b[(size_t)i3.y * H2S + lane];
        hv[14] = h2b[(size_t)i3.z * H2S + lane];
        hv[15] = h2b[(size_t)i3.w * H2S + lane];
#pragma unroll
        for (int u = 0; u < 16; ++u) a += bf2f(hv[u]);
    }
    if (j < je) {
        int4 i0 = *(const int4*)(csr + j);
        int4 i1 = *(const int4*)(csr + j + 4);
        unsigned short hv[8];
        hv[0] = h2b[(size_t)i0.x * H2S + lane];
        hv[1] = h2b[(size_t)i0.y * H2S + lane];
        hv[2] = h2b[(size_t)i0.z * H2S + lane];
        hv[3] = h2b[(size_t)i0.w * H2S + lane];
        hv[4] = h2b[(size_t)i1.x * H2S + lane];
        hv[5] = h2b[(size_t)i1.y * H2S + lane];
        hv[6] = h2b[(size_t)i1.z * H2S + lane];
        hv[7] = h2b[(size_t)i1.w * H2S + lane];
#pragma unroll
        for (int u = 0; u < 8; ++u) a += bf2f(hv[u]);
    }

    float v = act ? fmaf(di, a, b2[lane]) : -INFINITY;
    float m = v;
#pragma unroll
    for (int off = 32; off > 0; off >>= 1) m = fmaxf(m, __shfl_xor(m, off));
    float ex = act ? expf(v - m) : 0.f;
    float s = ex;
#pragma unroll
    for (int off = 32; off > 0; off >>= 1) s += __shfl_xor(s, off);
    float ls = logf(s);
    if (act) out[(long long)node * OUT_DIM + lane] = v - m - ls;
}

// ---------------- launch ----------------
extern "C" void kernel_launch(void* const* d_in, const int* in_sizes, int n_in,
                              void* d_out, int out_size, void* d_ws, size_t ws_size,
                              hipStream_t stream) {
    const float* x  = (const float*)d_in[0];
    const int*   ei = (const int*)d_in[1];
    const float* W1 = (const float*)d_in[2];
    const float* b1 = (const float*)d_in[3];
    const float* W2 = (const float*)d_in[4];
    const float* b2 = (const float*)d_in[5];
    float* out = (float*)d_out;

    const int* esrc = ei;
    const int* edst = ei + N_EDGES;

    char* w = (char*)d_ws;
    unsigned int* part = (unsigned int*)w;  w += sizeof(unsigned int) * (size_t)NB * BCAP;  // 8.0 MB
    int*    csr     = (int*)w;    w += sizeof(int) * (size_t)NB * SEGSTRIDE;  // 9.6 MB
    int*    row_beg = (int*)w;    w += sizeof(int) * NALLOC;
    int*    row_end = (int*)w;    w += sizeof(int) * NALLOC;
    float*  dinv    = (float*)w;  w += sizeof(float) * NALLOC;
    int*    gcursor = (int*)w;    w += sizeof(int) * 256;
    unsigned short* h1b = (unsigned short*)w;  w += sizeof(short) * (size_t)4 * NROWS * 32;  // sliced
    unsigned short* h1a = (unsigned short*)w;  w += sizeof(short) * (size_t)NROWS * HID_DIM;
    unsigned short* h2b = (unsigned short*)w;  w += sizeof(short) * (size_t)NROWS * H2S;
    unsigned short* w1t = (unsigned short*)w;  w += sizeof(short) * HID_DIM * IN_DIM;
    unsigned short* w2t = (unsigned short*)w;  w += sizeof(short) * N2 * HID_DIM;

    // prep (init + w1t + w2t fused)
    k_prep<<<1 + HID_DIM, 256, 0, stream>>>(W1, W2, gcursor, w1t, w2t, h1b, h2b);

    // CSR build (padded segments, fixed stride)
    k_part<<<NPB, 256, 0, stream>>>(esrc, edst, gcursor, part);
    k_bucket<<<NB, 256, 0, stream>>>(part, gcursor, row_beg, row_end, dinv, csr);

    // layer 1 GEMM via MFMA (pre-scaled by dinv), sliced output
    k_gemm1_mfma<<<(N_NODES + 63) / 64, 256, 0, stream>>>(x, w1t, dinv, h1b);

    // gather1 (+self+bias+ReLU) -> h1a: sliced, XCD-pair affine, 16 nodes/block
    k_layer1<<<12504, 256, 0, stream>>>(h1b, dinv, b1, row_beg, row_end, csr, h1a);

    // GEMM2 via MFMA -> h2b (pre-scaled by dinv)
    k_gemm2_mfma<<<NROWS / 64, 256, 0, stream>>>(h1a, w2t, dinv, h2b);

    // gather2 + log_softmax
    k_gather2<<<N_NODES / 4, 256, 0, stream>>>(h2b, dinv, b2, row_beg, row_end, csr, out);
}

// Round 14
// 160.066 us; speedup vs baseline: 1.4887x; 1.0019x over previous
//
#include <hip/hip_runtime.h>
#include <math.h>

#define N_NODES 50000
#define N_EDGES 1600000
#define IN_DIM 256
#define HID_DIM 128
#define OUT_DIM 40
#define N2 48          // OUT_DIM padded to MFMA multiple
#define H2S 40         // h2b row stride (elems): 4.0 MB -> L2 resident
#define ZROW N_NODES   // dedicated all-zero row index for CSR padding
#define NROWS 50048

#define NB 196         // dst buckets of 256 nodes
#define BCAP 10240     // part[] slots per bucket
#define SEGSTRIDE 12288
#define PCHUNK 4096
#define NPB ((N_EDGES + PCHUNK - 1) / PCHUNK)  // 391

typedef __attribute__((ext_vector_type(8))) short bf16x8;
typedef __attribute__((ext_vector_type(4))) float f32x4;
typedef __attribute__((ext_vector_type(2))) float f32x2;

// ---------------- bf16 helpers (RNE) ----------------
__device__ __forceinline__ unsigned int f2bf(float f) {
    unsigned int u = __float_as_uint(f);
    unsigned int r = u + 0x7FFFu + ((u >> 16) & 1u);
    return r >> 16;
}
__device__ __forceinline__ float bf2f(unsigned short s) {
    return __uint_as_float(((unsigned int)s) << 16);
}

// ---------------- prep: gcursor bases, zero rows, w1t, w2t ----------------
__global__ __launch_bounds__(256) void k_prep(const float* __restrict__ W1,
                                              const float* __restrict__ W2,
                                              int* __restrict__ gcursor,
                                              unsigned short* __restrict__ w1t,
                                              unsigned short* __restrict__ w2t,
                                              unsigned short* __restrict__ h1b,
                                              unsigned short* __restrict__ h2b) {
    const int b = blockIdx.x, t = threadIdx.x;
    if (b == 0) {
        if (t < NB) gcursor[t] = t * BCAP;
        if (t < HID_DIM) h1b[(size_t)ZROW * HID_DIM + t] = 0;
        if (t < H2S) h2b[(size_t)ZROW * H2S + t] = 0;
        for (int i = t; i < N2 * HID_DIM; i += 256) {
            int c = i >> 7, k = i & 127;
            w2t[i] = (c < OUT_DIM) ? (unsigned short)f2bf(W2[k * OUT_DIM + c]) : (unsigned short)0;
        }
    } else {
        int c = b - 1;
        w1t[c * IN_DIM + t] = (unsigned short)f2bf(W1[t * HID_DIM + c]);
    }
}

// ---------------- partition edges into 196 dst-buckets (4B packed) ----------------
__global__ __launch_bounds__(256) void k_part(const int* __restrict__ src,
                                              const int* __restrict__ dst,
                                              int* __restrict__ gcursor,
                                              unsigned int* __restrict__ part) {
    __shared__ int hist[NB];
    __shared__ int lcur[NB];
    const int tid = threadIdx.x;
    const int base = blockIdx.x * PCHUNK;
    const int n = min(PCHUNK, N_EDGES - base);

    for (int i = tid; i < NB; i += 256) hist[i] = 0;
    __syncthreads();
    for (int i = tid; i < n; i += 256)
        atomicAdd(&hist[dst[base + i] >> 8], 1);
    __syncthreads();
    for (int i = tid; i < NB; i += 256)
        lcur[i] = atomicAdd(&gcursor[i], hist[i]);
    __syncthreads();
    for (int i = tid; i < n; i += 256) {
        int d = dst[base + i];
        int g = d >> 8;
        int pos = atomicAdd(&lcur[g], 1);
        part[pos] = ((unsigned int)(d & 255) << 16) | (unsigned int)src[base + i];
    }
}

// ---------------- per-bucket counting sort: row_beg/row_end/dinv + padded csr ----------------
__global__ __launch_bounds__(256) void k_bucket(const unsigned int* __restrict__ part,
                                                const int* __restrict__ gcursor,
                                                int* __restrict__ row_beg,
                                                int* __restrict__ row_end,
                                                float* __restrict__ dinv,
                                                int* __restrict__ csr) {
    __shared__ int hist[256];
    __shared__ int sh[256];
    __shared__ int cur[256];
    const int g = blockIdx.x;
    const int tid = threadIdx.x;
    const int ebase = g * BCAP;
    const int ecnt = gcursor[g] - ebase;
    const int cbase = g * SEGSTRIDE;

    hist[tid] = 0;
    __syncthreads();
    for (int i = tid; i < ecnt; i += 256)
        atomicAdd(&hist[(part[ebase + i] >> 16) & 255], 1);
    __syncthreads();

    int own = hist[tid];
    int pcnt = (own + 7) & ~7;
    sh[tid] = pcnt;
    __syncthreads();
    for (int off = 1; off < 256; off <<= 1) {
        int t = (tid >= off) ? sh[tid - off] : 0;
        __syncthreads();
        sh[tid] += t;
        __syncthreads();
    }
    int pexcl = sh[tid] - pcnt;

    int node = (g << 8) + tid;
    if (node < N_NODES) {
        row_beg[node] = cbase + pexcl;
        row_end[node] = cbase + pexcl + pcnt;
        dinv[node] = rsqrtf((float)own + 1.0f);
    }
    cur[tid] = cbase + pexcl;
    for (int p = own; p < pcnt; ++p) csr[cbase + pexcl + p] = ZROW;
    __syncthreads();

    for (int i = tid; i < ecnt; i += 256) {
        unsigned int p = part[ebase + i];
        int pos = atomicAdd(&cur[(p >> 16) & 255], 1);
        csr[pos] = (int)(p & 0xFFFFu);
    }
}

// ---------------- GEMM1 (MFMA): h1b[N][128](bf16) = dinv * (x @ W1), 64-row tile ----------------
__global__ __launch_bounds__(256) void k_gemm1_mfma(const float* __restrict__ x,
                                                    const unsigned short* __restrict__ w1t,
                                                    const float* __restrict__ dinv,
                                                    unsigned short* __restrict__ h1b) {
    __shared__ unsigned short Asub[64 * 32];
    __shared__ unsigned short Bsub[128 * 32];
    const int tid  = threadIdx.x;
    const int w    = tid >> 6;
    const int lane = tid & 63;
    const int row0 = blockIdx.x * 64;
    const int r  = lane & 15;
    const int kg = lane >> 4;

    f32x4 acc[8] = {};

    for (int k0 = 0; k0 < IN_DIM; k0 += 32) {
        {
            int ar = tid >> 2, as = tid & 3;
            int asw = as ^ (ar & 3);
            uint4 pk = make_uint4(0, 0, 0, 0);
            int grow = row0 + ar;
            if (grow < N_NODES) {
                const float4* p = (const float4*)(x + (size_t)grow * IN_DIM + k0 + as * 8);
                float4 v0 = p[0], v1 = p[1];
                pk.x = f2bf(v0.x) | (f2bf(v0.y) << 16);
                pk.y = f2bf(v0.z) | (f2bf(v0.w) << 16);
                pk.z = f2bf(v1.x) | (f2bf(v1.y) << 16);
                pk.w = f2bf(v1.z) | (f2bf(v1.w) << 16);
            }
            *(uint4*)(Asub + ar * 32 + asw * 8) = pk;
        }
#pragma unroll
        for (int i = 0; i < 2; ++i) {
            int q = tid + i * 256;
            int col = q >> 2, slot = q & 3;
            int sl2 = slot ^ (col & 3);
            *(uint4*)(Bsub + col * 32 + sl2 * 8) =
                *(const uint4*)(w1t + (size_t)col * IN_DIM + k0 + slot * 8);
        }
        __syncthreads();

        bf16x8 af = *(const bf16x8*)(Asub + (w * 16 + r) * 32 + ((kg ^ (r & 3)) * 8));
#pragma unroll
        for (int f = 0; f < 8; ++f) {
            bf16x8 bfr = *(const bf16x8*)(Bsub + (f * 16 + r) * 32 + ((kg ^ (r & 3)) * 8));
            acc[f] = __builtin_amdgcn_mfma_f32_16x16x32_bf16(af, bfr, acc[f], 0, 0, 0);
        }
        __syncthreads();
    }

    float dv[4];
#pragma unroll
    for (int v = 0; v < 4; ++v) {
        int gr = row0 + w * 16 + kg * 4 + v;
        dv[v] = (gr < N_NODES) ? dinv[gr] : 0.f;
    }
#pragma unroll
    for (int f = 0; f < 8; ++f)
#pragma unroll
        for (int v = 0; v < 4; ++v) {
            int gr = row0 + w * 16 + kg * 4 + v;
            if (gr < N_NODES)
                h1b[(size_t)gr * HID_DIM + f * 16 + r] = (unsigned short)f2bf(acc[f][v] * dv[v]);
        }
}

// ---------------- layer-1 gather (round-12 proven form): h1a = relu(di*sum + b1) ----------------
__global__ __launch_bounds__(256) void k_layer1(const unsigned short* __restrict__ h1b,
                                                const float* __restrict__ dinv,
                                                const float* __restrict__ b1,
                                                const int* __restrict__ row_beg,
                                                const int* __restrict__ row_end,
                                                const int* __restrict__ csr,
                                                unsigned short* __restrict__ h1a) {
    const int w    = threadIdx.x >> 6;
    const int lane = threadIdx.x & 63;
    const int c0   = lane * 2;
    const float bb0 = b1[c0], bb1 = b1[c0 + 1];

    const int node = blockIdx.x * 4 + w;
    const float di = dinv[node];

    unsigned int us = *(const unsigned int*)(h1b + (size_t)node * HID_DIM + c0);
    f32x2 acc;
    acc.x = bf2f((unsigned short)us);
    acc.y = bf2f((unsigned short)(us >> 16));

    int j = row_beg[node];
    const int je = row_end[node];
    for (; j + 16 <= je; j += 16) {
        int4 i0 = *(const int4*)(csr + j);
        int4 i1 = *(const int4*)(csr + j + 4);
        int4 i2 = *(const int4*)(csr + j + 8);
        int4 i3 = *(const int4*)(csr + j + 12);
        unsigned int uu[16];
        uu[0]  = *(const unsigned int*)(h1b + (size_t)i0.x * HID_DIM + c0);
        uu[1]  = *(const unsigned int*)(h1b + (size_t)i0.y * HID_DIM + c0);
        uu[2]  = *(const unsigned int*)(h1b + (size_t)i0.z * HID_DIM + c0);
        uu[3]  = *(const unsigned int*)(h1b + (size_t)i0.w * HID_DIM + c0);
        uu[4]  = *(const unsigned int*)(h1b + (size_t)i1.x * HID_DIM + c0);
        uu[5]  = *(const unsigned int*)(h1b + (size_t)i1.y * HID_DIM + c0);
        uu[6]  = *(const unsigned int*)(h1b + (size_t)i1.z * HID_DIM + c0);
        uu[7]  = *(const unsigned int*)(h1b + (size_t)i1.w * HID_DIM + c0);
        uu[8]  = *(const unsigned int*)(h1b + (size_t)i2.x * HID_DIM + c0);
        uu[9]  = *(const unsigned int*)(h1b + (size_t)i2.y * HID_DIM + c0);
        uu[10] = *(const unsigned int*)(h1b + (size_t)i2.z * HID_DIM + c0);
        uu[11] = *(const unsigned int*)(h1b + (size_t)i2.w * HID_DIM + c0);
        uu[12] = *(const unsigned int*)(h1b + (size_t)i3.x * HID_DIM + c0);
        uu[13] = *(const unsigned int*)(h1b + (size_t)i3.y * HID_DIM + c0);
        uu[14] = *(const unsigned int*)(h1b + (size_t)i3.z * HID_DIM + c0);
        uu[15] = *(const unsigned int*)(h1b + (size_t)i3.w * HID_DIM + c0);
#pragma unroll
        for (int u = 0; u < 16; ++u) {
            f32x2 t;
            t.x = __uint_as_float(uu[u] << 16);
            t.y = __uint_as_float(uu[u] & 0xffff0000u);
            acc += t;
        }
    }
    if (j < je) {  // exactly one 8-batch remains
        int4 i0 = *(const int4*)(csr + j);
        int4 i1 = *(const int4*)(csr + j + 4);
        unsigned int uu[8];
        uu[0] = *(const unsigned int*)(h1b + (size_t)i0.x * HID_DIM + c0);
        uu[1] = *(const unsigned int*)(h1b + (size_t)i0.y * HID_DIM + c0);
        uu[2] = *(const unsigned int*)(h1b + (size_t)i0.z * HID_DIM + c0);
        uu[3] = *(const unsigned int*)(h1b + (size_t)i0.w * HID_DIM + c0);
        uu[4] = *(const unsigned int*)(h1b + (size_t)i1.x * HID_DIM + c0);
        uu[5] = *(const unsigned int*)(h1b + (size_t)i1.y * HID_DIM + c0);
        uu[6] = *(const unsigned int*)(h1b + (size_t)i1.z * HID_DIM + c0);
        uu[7] = *(const unsigned int*)(h1b + (size_t)i1.w * HID_DIM + c0);
#pragma unroll
        for (int u = 0; u < 8; ++u) {
            f32x2 t;
            t.x = __uint_as_float(uu[u] << 16);
            t.y = __uint_as_float(uu[u] & 0xffff0000u);
            acc += t;
        }
    }

    float r0 = fmaxf(fmaf(di, acc.x, bb0), 0.f);
    float r1 = fmaxf(fmaf(di, acc.y, bb1), 0.f);
    *(unsigned int*)(h1a + (size_t)node * HID_DIM + c0) = f2bf(r0) | (f2bf(r1) << 16);
}

// ---------------- GEMM2 (MFMA): h2b[N][40](bf16) = dinv * (h1a @ W2) ----------------
__global__ __launch_bounds__(256) void k_gemm2_mfma(const unsigned short* __restrict__ h1a,
                                                    const unsigned short* __restrict__ w2t,
                                                    const float* __restrict__ dinv,
                                                    unsigned short* __restrict__ h2b) {
    __shared__ unsigned short Bs[N2 * HID_DIM];  // 12 KB
    const int tid = threadIdx.x;
#pragma unroll
    for (int i = tid; i < N2 * HID_DIM / 8; i += 256) {
        int row = i >> 4, slot = i & 15;
        *(uint4*)(Bs + row * HID_DIM + (slot ^ (row & 7)) * 8) =
            *(const uint4*)(w2t + (size_t)row * HID_DIM + slot * 8);
    }
    __syncthreads();

    const int w    = tid >> 6;
    const int lane = tid & 63;
    const int r  = lane & 15;
    const int kg = lane >> 4;
    const int row0 = blockIdx.x * 64 + w * 16;

    bf16x8 bfr[4][3];
#pragma unroll
    for (int ks = 0; ks < 4; ++ks)
#pragma unroll
        for (int f = 0; f < 3; ++f) {
            int row = f * 16 + r;
            int slot = ks * 4 + kg;
            bfr[ks][f] = *(const bf16x8*)(Bs + row * HID_DIM + (slot ^ (row & 7)) * 8);
        }

    f32x4 acc[3] = {};
#pragma unroll
    for (int ks = 0; ks < 4; ++ks) {
        bf16x8 af = *(const bf16x8*)(h1a + (size_t)(row0 + r) * HID_DIM + ks * 32 + kg * 8);
#pragma unroll
        for (int f = 0; f < 3; ++f)
            acc[f] = __builtin_amdgcn_mfma_f32_16x16x32_bf16(af, bfr[ks][f], acc[f], 0, 0, 0);
    }

    float dv[4];
#pragma unroll
    for (int v = 0; v < 4; ++v) {
        int gr = row0 + kg * 4 + v;
        dv[v] = (gr < N_NODES) ? dinv[gr] : 0.f;
    }
#pragma unroll
    for (int f = 0; f < 3; ++f) {
        int col = f * 16 + r;
        if (col < OUT_DIM) {
#pragma unroll
            for (int v = 0; v < 4; ++v) {
                int gr = row0 + kg * 4 + v;
                if (gr < N_NODES)
                    h2b[(size_t)gr * H2S + col] = (unsigned short)f2bf(acc[f][v] * dv[v]);
            }
        }
    }
}

// ---------------- gather layer 2 (lane-clamped) + bias + log_softmax ----------------
// lanes >= OUT_DIM clamp to col 39: their loads hit the SAME cache line as the
// active lanes (no random extra-line touches), results masked in the epilogue.
__global__ __launch_bounds__(256) void k_gather2(const unsigned short* __restrict__ h2b,
                                                 const float* __restrict__ dinv,
                                                 const float* __restrict__ b2,
                                                 const int* __restrict__ row_beg,
                                                 const int* __restrict__ row_end,
                                                 const int* __restrict__ csr,
                                                 float* __restrict__ out) {
    const int node = blockIdx.x * 4 + (threadIdx.x >> 6);
    const int lane = threadIdx.x & 63;
    const bool act = lane < OUT_DIM;
    const int  cl  = act ? lane : (OUT_DIM - 1);  // clamped column
    const float di = dinv[node];

    float a = bf2f(h2b[(size_t)node * H2S + cl]);

    int j = row_beg[node];
    const int je = row_end[node];
    for (; j + 16 <= je; j += 16) {
        int4 i0 = *(const int4*)(csr + j);
        int4 i1 = *(const int4*)(csr + j + 4);
        int4 i2 = *(const int4*)(csr + j + 8);
        int4 i3 = *(const int4*)(csr + j + 12);
        unsigned short hv[16];
        hv[0]  = h2b[(size_t)i0.x * H2S + cl];
        hv[1]  = h2b[(size_t)i0.y * H2S + cl];
        hv[2]  = h2b[(size_t)i0.z * H2S + cl];
        hv[3]  = h2b[(size_t)i0.w * H2S + cl];
        hv[4]  = h2b[(size_t)i1.x * H2S + cl];
        hv[5]  = h2b[(size_t)i1.y * H2S + cl];
        hv[6]  = h2b[(size_t)i1.z * H2S + cl];
        hv[7]  = h2b[(size_t)i1.w * H2S + cl];
        hv[8]  = h2b[(size_t)i2.x * H2S + cl];
        hv[9]  = h2b[(size_t)i2.y * H2S + cl];
        hv[10] = h2b[(size_t)i2.z * H2S + cl];
        hv[11] = h2b[(size_t)i2.w * H2S + cl];
        hv[12] = h2b[(size_t)i3.x * H2S + cl];
        hv[13] = h2b[(size_t)i3.y * H2S + cl];
        hv[14] = h2b[(size_t)i3.z * H2S + cl];
        hv[15] = h2b[(size_t)i3.w * H2S + cl];
#pragma unroll
        for (int u = 0; u < 16; ++u) a += bf2f(hv[u]);
    }
    if (j < je) {
        int4 i0 = *(const int4*)(csr + j);
        int4 i1 = *(const int4*)(csr + j + 4);
        unsigned short hv[8];
        hv[0] = h2b[(size_t)i0.x * H2S + cl];
        hv[1] = h2b[(size_t)i0.y * H2S + cl];
        hv[2] = h2b[(size_t)i0.z * H2S + cl];
        hv[3] = h2b[(size_t)i0.w * H2S + cl];
        hv[4] = h2b[(size_t)i1.x * H2S + cl];
        hv[5] = h2b[(size_t)i1.y * H2S + cl];
        hv[6] = h2b[(size_t)i1.z * H2S + cl];
        hv[7] = h2b[(size_t)i1.w * H2S + cl];
#pragma unroll
        for (int u = 0; u < 8; ++u) a += bf2f(hv[u]);
    }

    float v = act ? fmaf(di, a, b2[cl]) : -INFINITY;
    float m = v;
#pragma unroll
    for (int off = 32; off > 0; off >>= 1) m = fmaxf(m, __shfl_xor(m, off));
    float ex = act ? expf(v - m) : 0.f;
    float s = ex;
#pragma unroll
    for (int off = 32; off > 0; off >>= 1) s += __shfl_xor(s, off);
    float ls = logf(s);
    if (act) out[(long long)node * OUT_DIM + lane] = v - m - ls;
}

// ---------------- launch ----------------
extern "C" void kernel_launch(void* const* d_in, const int* in_sizes, int n_in,
                              void* d_out, int out_size, void* d_ws, size_t ws_size,
                              hipStream_t stream) {
    const float* x  = (const float*)d_in[0];
    const int*   ei = (const int*)d_in[1];
    const float* W1 = (const float*)d_in[2];
    const float* b1 = (const float*)d_in[3];
    const float* W2 = (const float*)d_in[4];
    const float* b2 = (const float*)d_in[5];
    float* out = (float*)d_out;

    const int* esrc = ei;
    const int* edst = ei + N_EDGES;

    char* w = (char*)d_ws;
    unsigned int* part = (unsigned int*)w;  w += sizeof(unsigned int) * (size_t)NB * BCAP;  // 8.0 MB
    int*    csr     = (int*)w;    w += sizeof(int) * (size_t)NB * SEGSTRIDE;  // 9.6 MB
    int*    row_beg = (int*)w;    w += sizeof(int) * NROWS;
    int*    row_end = (int*)w;    w += sizeof(int) * NROWS;
    float*  dinv    = (float*)w;  w += sizeof(float) * NROWS;
    int*    gcursor = (int*)w;    w += sizeof(int) * 256;
    unsigned short* h1b = (unsigned short*)w;  w += sizeof(short) * (size_t)NROWS * HID_DIM;
    unsigned short* h1a = (unsigned short*)w;  w += sizeof(short) * (size_t)NROWS * HID_DIM;
    unsigned short* h2b = (unsigned short*)w;  w += sizeof(short) * (size_t)NROWS * H2S;
    unsigned short* w1t = (unsigned short*)w;  w += sizeof(short) * HID_DIM * IN_DIM;
    unsigned short* w2t = (unsigned short*)w;  w += sizeof(short) * N2 * HID_DIM;

    // prep (init + w1t + w2t fused)
    k_prep<<<1 + HID_DIM, 256, 0, stream>>>(W1, W2, gcursor, w1t, w2t, h1b, h2b);

    // CSR build (padded segments, fixed stride)
    k_part<<<NPB, 256, 0, stream>>>(esrc, edst, gcursor, part);
    k_bucket<<<NB, 256, 0, stream>>>(part, gcursor, row_beg, row_end, dinv, csr);

    // layer 1 GEMM via MFMA (pre-scaled by dinv), 64-row tiles
    k_gemm1_mfma<<<(N_NODES + 63) / 64, 256, 0, stream>>>(x, w1t, dinv, h1b);

    // gather1 (+self+bias+ReLU) -> h1a (round-12 proven form)
    k_layer1<<<N_NODES / 4, 256, 0, stream>>>(h1b, dinv, b1, row_beg, row_end, csr, h1a);

    // GEMM2 via MFMA -> h2b (pre-scaled by dinv)
    k_gemm2_mfma<<<NROWS / 64, 256, 0, stream>>>(h1a, w2t, dinv, h2b);

    // gather2 + log_softmax (lane-clamped)
    k_gather2<<<N_NODES / 4, 256, 0, stream>>>(h2b, dinv, b2, row_beg, row_end, csr, out);
}